// Round 1
// baseline (122.999 us; speedup 1.0000x reference)
//
#include <hip/hip_runtime.h>
#include <hip/hip_bf16.h>

typedef __bf16 bf16_t;
typedef __bf16 bf16x8 __attribute__((ext_vector_type(8)));
typedef float f32x4 __attribute__((ext_vector_type(4)));

static_assert(sizeof(bf16x8) == 16, "bf16x8 must be 16B");

// Problem constants
#define BB 2
#define SS 2048
#define DD 512
#define HH 8
#define DH 64
// HID == 512; head block = contiguous [2048,64] at (b*8+h)*131072

// ---------------- cast q,k,v f32 -> bf16 (vectorized) ----------------
__global__ void cast_qkv(const float* __restrict__ q, const float* __restrict__ k,
                         const float* __restrict__ v, bf16_t* __restrict__ dst, int n) {
  const float* src = (blockIdx.z == 0) ? q : (blockIdx.z == 1) ? k : v;
  bf16_t* out = dst + (size_t)blockIdx.z * n;
  int i = (blockIdx.x * 256 + threadIdx.x) * 8;
  if (i >= n) return;
  const float4* s4 = (const float4*)(src + i);
  float4 a = s4[0], b = s4[1];
  bf16x8 o;
  o[0] = (bf16_t)a.x; o[1] = (bf16_t)a.y; o[2] = (bf16_t)a.z; o[3] = (bf16_t)a.w;
  o[4] = (bf16_t)b.x; o[5] = (bf16_t)b.y; o[6] = (bf16_t)b.z; o[7] = (bf16_t)b.w;
  *(bf16x8*)(out + i) = o;
}

// ------------- transpose + cast weights: Wt[n][k] = (bf16)W[k][n] -------------
__global__ void transpose_w(const float* __restrict__ w0, const float* __restrict__ w1,
                            const float* __restrict__ w2, const float* __restrict__ w3,
                            bf16_t* __restrict__ wt) {
  __shared__ float tile[32][33];
  const float* W = (blockIdx.z == 0) ? w0 : (blockIdx.z == 1) ? w1 : (blockIdx.z == 2) ? w2 : w3;
  bf16_t* out = wt + (size_t)blockIdx.z * 512 * 512;
  int tx = threadIdx.x, ty = threadIdx.y;          // block (32,8)
  int nb = blockIdx.x * 32, kb = blockIdx.y * 32;
#pragma unroll
  for (int i = 0; i < 4; i++)
    tile[ty + i * 8][tx] = W[(size_t)(kb + ty + i * 8) * 512 + nb + tx];
  __syncthreads();
#pragma unroll
  for (int i = 0; i < 4; i++)
    out[(size_t)(nb + ty + i * 8) * 512 + kb + tx] = (bf16_t)tile[tx][ty + i * 8];
}

// ------------- GEMM: C[M,N] = A[M,K] @ Bt[N,K]^T + bias[N] -------------
// 128x128 tile, BK=64, 256 thr (4 waves 2x2), global_load_lds(16B), dbuf LDS.
template <typename OutT>
__global__ __launch_bounds__(256) void gemm_bt(
    const bf16_t* __restrict__ Abase, const bf16_t* __restrict__ Btbase,
    const float* __restrict__ bias0, const float* __restrict__ bias1,
    const float* __restrict__ bias2, OutT* __restrict__ Cbase,
    int M, int N, int K, long Az, long Bz, long Cz) {
  const bf16_t* A  = Abase + (size_t)blockIdx.z * Az;
  const bf16_t* Bt = Btbase + (size_t)blockIdx.z * Bz;
  const float* bias = (blockIdx.z == 0) ? bias0 : (blockIdx.z == 1) ? bias1 : bias2;
  OutT* C = Cbase + (size_t)blockIdx.z * Cz;

  __shared__ bf16_t As[2][128 * 64];
  __shared__ bf16_t Bs[2][128 * 64];

  const int tid = threadIdx.x, w = tid >> 6, l = tid & 63;
  const int bm = blockIdx.y, bn = blockIdx.x;
  const int wm = (w >> 1) * 64, wn = (w & 1) * 64;
  const int lr = l & 15, lg = l >> 4;

  f32x4 acc[4][4] = {};

  auto stage = [&](int buf, int kt) {
#pragma unroll
    for (int j = 0; j < 4; j++) {
      int lin = (j * 4 + w) * 64 + l;       // 16B-chunk index 0..1023
      int row = lin >> 3, cc = lin & 7;
      const bf16_t* g = A + (size_t)(bm * 128 + row) * K + kt * 64 + cc * 8;
      __builtin_amdgcn_global_load_lds(
          (const __attribute__((address_space(1))) void*)g,
          (__attribute__((address_space(3))) void*)(&As[buf][(j * 4 + w) * 512]), 16, 0, 0);
    }
#pragma unroll
    for (int j = 0; j < 4; j++) {
      int lin = (j * 4 + w) * 64 + l;
      int row = lin >> 3, cc = lin & 7;
      const bf16_t* g = Bt + (size_t)(bn * 128 + row) * K + kt * 64 + cc * 8;
      __builtin_amdgcn_global_load_lds(
          (const __attribute__((address_space(1))) void*)g,
          (__attribute__((address_space(3))) void*)(&Bs[buf][(j * 4 + w) * 512]), 16, 0, 0);
    }
  };

  stage(0, 0);
  const int KT = K >> 6;
  for (int kt = 0; kt < KT; kt++) {
    __syncthreads();                         // drains vmcnt -> buf[kt&1] ready
    if (kt + 1 < KT) stage((kt + 1) & 1, kt + 1);
    const bf16_t* as = As[kt & 1];
    const bf16_t* bs = Bs[kt & 1];
#pragma unroll
    for (int kc = 0; kc < 2; kc++) {
      bf16x8 a[4], b[4];
#pragma unroll
      for (int i = 0; i < 4; i++)
        a[i] = *(const bf16x8*)(as + (wm + i * 16 + lr) * 64 + kc * 32 + lg * 8);
#pragma unroll
      for (int i = 0; i < 4; i++)
        b[i] = *(const bf16x8*)(bs + (wn + i * 16 + lr) * 64 + kc * 32 + lg * 8);
#pragma unroll
      for (int i = 0; i < 4; i++)
#pragma unroll
        for (int j = 0; j < 4; j++)
          acc[i][j] = __builtin_amdgcn_mfma_f32_16x16x32_bf16(a[i], b[j], acc[i][j], 0, 0, 0);
    }
  }

  // epilogue: C row = (lane>>4)*4+reg, col = lane&15 (verified m89/m91 layout)
  const int row0 = bm * 128 + wm, col0 = bn * 128 + wn;
#pragma unroll
  for (int j = 0; j < 4; j++) {
    int col = col0 + j * 16 + lr;
    float bv = bias[col];
#pragma unroll
    for (int i = 0; i < 4; i++) {
      int row = row0 + i * 16 + lg * 4;
#pragma unroll
      for (int r = 0; r < 4; r++) {
        float vv = acc[i][j][r] + bv;
        C[(size_t)(row + r) * N + col] = (OutT)vv;
      }
    }
  }
}

// ------------- flash attention per head-block -------------
// grid (32 qtiles, 16 bh), 256 thr (4 waves); QBLK=64 (16 q-rows/wave), KVBLK=64.
// NOTE: reference divides by sqrt(DH)=8 AFTER softmax -> fold into epilogue.
__global__ __launch_bounds__(256) void attn_flash(const bf16_t* __restrict__ qp,
                                                  const bf16_t* __restrict__ kp,
                                                  const bf16_t* __restrict__ vp,
                                                  bf16_t* __restrict__ ctx) {
  const int qt = blockIdx.x, bh = blockIdx.y;
  const int tid = threadIdx.x, w = tid >> 6, l = tid & 63;
  const int lr = l & 15, lg = l >> 4;
  const size_t hb = (size_t)bh * (SS * DH);        // contiguous [2048,64] head block
  const bf16_t* Q = qp + hb;
  const bf16_t* Kh = kp + hb;
  const bf16_t* Vh = vp + hb;

  __shared__ bf16_t Ks[64][72];    // [kv][d], pad 72 (144B rows, 16B aligned)
  __shared__ bf16_t Vt[64][72];    // [d][kv] transposed
  __shared__ bf16_t Ps[4][16][72]; // per-wave P transpose buffer

  const int qr0 = qt * 64 + w * 16;

  // Q fragments held in registers for the whole kernel
  bf16x8 aq[2];
#pragma unroll
  for (int kc = 0; kc < 2; kc++)
    aq[kc] = *(const bf16x8*)(Q + (size_t)(qr0 + lr) * DH + kc * 32 + lg * 8);

  f32x4 o[4] = {};
  float m_r[4], l_r[4];
#pragma unroll
  for (int r = 0; r < 4; r++) { m_r[r] = -1e30f; l_r[r] = 0.f; }

  for (int it = 0; it < 32; it++) {
    const int kv0 = it * 64;
    __syncthreads();                               // prev tile's reads done
    // --- stage K row-major, V transposed ---
    bf16x8 kreg[2], vreg[2];
    int krow[2], kcc[2], vkv[2], vdc[2];
#pragma unroll
    for (int i = 0; i < 2; i++) {
      int c = i * 256 + tid;                       // 0..511 chunks of 8 elems
      krow[i] = c >> 3; kcc[i] = c & 7;
      kreg[i] = *(const bf16x8*)(Kh + (size_t)(kv0 + krow[i]) * DH + kcc[i] * 8);
      vkv[i] = c & 63; vdc[i] = (c >> 6) & 7;
      vreg[i] = *(const bf16x8*)(Vh + (size_t)(kv0 + vkv[i]) * DH + vdc[i] * 8);
    }
#pragma unroll
    for (int i = 0; i < 2; i++) {
      *(bf16x8*)(&Ks[krow[i]][kcc[i] * 8]) = kreg[i];
#pragma unroll
      for (int j = 0; j < 8; j++) Vt[vdc[i] * 8 + j][vkv[i]] = vreg[i][j];
    }
    __syncthreads();                               // staged tile visible

    // --- S = Q @ K^T ---
    f32x4 s[4] = {};
#pragma unroll
    for (int kc = 0; kc < 2; kc++) {
#pragma unroll
      for (int n = 0; n < 4; n++) {
        bf16x8 bk = *(const bf16x8*)(&Ks[n * 16 + lr][kc * 32 + lg * 8]);
        s[n] = __builtin_amdgcn_mfma_f32_16x16x32_bf16(aq[kc], bk, s[n], 0, 0, 0);
      }
    }

    // --- online softmax: row r lives in reg r across the 16 lanes of a group ---
    float p[4][4];
#pragma unroll
    for (int r = 0; r < 4; r++) {
      float tmax = fmaxf(fmaxf(s[0][r], s[1][r]), fmaxf(s[2][r], s[3][r]));
#pragma unroll
      for (int msk = 1; msk < 16; msk <<= 1) tmax = fmaxf(tmax, __shfl_xor(tmax, msk));
      float mnew = fmaxf(m_r[r], tmax);
      float scale = __expf(m_r[r] - mnew);
      float rs = 0.f;
#pragma unroll
      for (int n = 0; n < 4; n++) { p[n][r] = __expf(s[n][r] - mnew); rs += p[n][r]; }
#pragma unroll
      for (int msk = 1; msk < 16; msk <<= 1) rs += __shfl_xor(rs, msk);
      l_r[r] = l_r[r] * scale + rs;
      m_r[r] = mnew;
#pragma unroll
      for (int n = 0; n < 4; n++) o[n][r] *= scale;
    }

    // --- transpose P via per-wave LDS (C-layout -> A-fragment layout) ---
#pragma unroll
    for (int n = 0; n < 4; n++)
#pragma unroll
      for (int r = 0; r < 4; r++)
        Ps[w][lg * 4 + r][n * 16 + lr] = (bf16_t)p[n][r];
    __syncthreads();                               // safety: cross-lane LDS RAW

    // --- O += P @ V ---
#pragma unroll
    for (int kc = 0; kc < 2; kc++) {
      bf16x8 pa = *(const bf16x8*)(&Ps[w][lr][kc * 32 + lg * 8]);
#pragma unroll
      for (int n = 0; n < 4; n++) {
        bf16x8 bv = *(const bf16x8*)(&Vt[n * 16 + lr][kc * 32 + lg * 8]);
        o[n] = __builtin_amdgcn_mfma_f32_16x16x32_bf16(pa, bv, o[n], 0, 0, 0);
      }
    }
  }

  // epilogue: ctx[b*S + t][h*64 + d] = O / (l * 8)
  const int b = bh >> 3, h = bh & 7;
#pragma unroll
  for (int r = 0; r < 4; r++) {
    float inv = 1.0f / (l_r[r] * 8.0f);
    int t = qr0 + lg * 4 + r;
    size_t rowbase = ((size_t)b * SS + t) * 512 + h * 64;
#pragma unroll
    for (int n = 0; n < 4; n++)
      ctx[rowbase + n * 16 + lr] = (bf16_t)(o[n][r] * inv);
  }
}

// ---------------- launcher ----------------
extern "C" void kernel_launch(void* const* d_in, const int* in_sizes, int n_in,
                              void* d_out, int out_size, void* d_ws, size_t ws_size,
                              hipStream_t stream) {
  const float* q  = (const float*)d_in[0];
  const float* k  = (const float*)d_in[1];
  const float* v  = (const float*)d_in[2];
  const float* Wq = (const float*)d_in[3];
  const float* bq = (const float*)d_in[4];
  const float* Wk = (const float*)d_in[5];
  const float* bk = (const float*)d_in[6];
  const float* Wv = (const float*)d_in[7];
  const float* bv = (const float*)d_in[8];
  const float* Wo = (const float*)d_in[9];
  const float* bo = (const float*)d_in[10];

  const size_t NQKV = (size_t)4096 * 512;   // 2,097,152 elems per tensor
  const size_t NW = (size_t)512 * 512;

  bf16_t* ws  = (bf16_t*)d_ws;
  bf16_t* qkvb = ws;                 // 3*NQKV  (qb,kb,vb)
  bf16_t* wt   = qkvb + 3 * NQKV;    // 4*NW    (Wqt,Wkt,Wvt,Wot)
  bf16_t* proj = wt + 4 * NW;        // 3*NQKV  (qp,kp,vp)
  bf16_t* ctx  = proj + 3 * NQKV;    // NQKV
  // total 30 MB

  // 1. cast q,k,v -> bf16
  cast_qkv<<<dim3(1024, 1, 3), 256, 0, stream>>>(q, k, v, qkvb, (int)NQKV);
  // 2. transpose+cast weights
  transpose_w<<<dim3(16, 16, 4), dim3(32, 8), 0, stream>>>(Wq, Wk, Wv, Wo, wt);
  // 3. fused QKV projections (z-batched)
  gemm_bt<bf16_t><<<dim3(4, 32, 3), 256, 0, stream>>>(
      qkvb, wt, bq, bk, bv, proj, 4096, 512, 512, (long)NQKV, (long)NW, (long)NQKV);
  // 4. flash attention per head
  attn_flash<<<dim3(32, 16), 256, 0, stream>>>(proj, proj + NQKV, proj + 2 * NQKV, ctx);
  // 5. output projection (f32 out)
  gemm_bt<float><<<dim3(4, 32, 1), 256, 0, stream>>>(
      ctx, wt + 3 * NW, bo, bo, bo, (float*)d_out, 4096, 512, 512, 0, 0, 0);
}

// Round 2
// 110.558 us; speedup vs baseline: 1.1125x; 1.1125x over previous
//
#include <hip/hip_runtime.h>
#include <hip/hip_bf16.h>

typedef __bf16 bf16_t;
typedef __bf16 bf16x8 __attribute__((ext_vector_type(8)));
typedef float f32x4 __attribute__((ext_vector_type(4)));

static_assert(sizeof(bf16x8) == 16, "bf16x8 must be 16B");

// Problem constants
#define BB 2
#define SS 2048
#define DD 512
#define HH 8
#define DH 64
// HID == 512; head block = contiguous [2048,64] at (b*8+h)*131072

// ---------------- cast q,k,v f32 -> bf16 (vectorized) ----------------
__global__ void cast_qkv(const float* __restrict__ q, const float* __restrict__ k,
                         const float* __restrict__ v, bf16_t* __restrict__ dst, int n) {
  const float* src = (blockIdx.z == 0) ? q : (blockIdx.z == 1) ? k : v;
  bf16_t* out = dst + (size_t)blockIdx.z * n;
  int i = (blockIdx.x * 256 + threadIdx.x) * 8;
  if (i >= n) return;
  const float4* s4 = (const float4*)(src + i);
  float4 a = s4[0], b = s4[1];
  bf16x8 o;
  o[0] = (bf16_t)a.x; o[1] = (bf16_t)a.y; o[2] = (bf16_t)a.z; o[3] = (bf16_t)a.w;
  o[4] = (bf16_t)b.x; o[5] = (bf16_t)b.y; o[6] = (bf16_t)b.z; o[7] = (bf16_t)b.w;
  *(bf16x8*)(out + i) = o;
}

// ------------- transpose + cast weights: Wt[n][k] = (bf16)W[k][n] -------------
__global__ void transpose_w(const float* __restrict__ w0, const float* __restrict__ w1,
                            const float* __restrict__ w2, const float* __restrict__ w3,
                            bf16_t* __restrict__ wt) {
  __shared__ float tile[32][33];
  const float* W = (blockIdx.z == 0) ? w0 : (blockIdx.z == 1) ? w1 : (blockIdx.z == 2) ? w2 : w3;
  bf16_t* out = wt + (size_t)blockIdx.z * 512 * 512;
  int tx = threadIdx.x, ty = threadIdx.y;          // block (32,8)
  int nb = blockIdx.x * 32, kb = blockIdx.y * 32;
#pragma unroll
  for (int i = 0; i < 4; i++)
    tile[ty + i * 8][tx] = W[(size_t)(kb + ty + i * 8) * 512 + nb + tx];
  __syncthreads();
#pragma unroll
  for (int i = 0; i < 4; i++)
    out[(size_t)(nb + ty + i * 8) * 512 + kb + tx] = (bf16_t)tile[tx][ty + i * 8];
}

// ------------- GEMM: C[M,N] = A[M,K] @ Bt[N,K]^T + bias[N] -------------
// 128x128 tile, BK=64, 256 thr (4 waves 2x2), global_load_lds(16B), dbuf LDS.
template <typename OutT>
__global__ __launch_bounds__(256) void gemm_bt(
    const bf16_t* __restrict__ Abase, const bf16_t* __restrict__ Btbase,
    const float* __restrict__ bias0, const float* __restrict__ bias1,
    const float* __restrict__ bias2, OutT* __restrict__ Cbase,
    int M, int N, int K, long Az, long Bz, long Cz) {
  const bf16_t* A  = Abase + (size_t)blockIdx.z * Az;
  const bf16_t* Bt = Btbase + (size_t)blockIdx.z * Bz;
  const float* bias = (blockIdx.z == 0) ? bias0 : (blockIdx.z == 1) ? bias1 : bias2;
  OutT* C = Cbase + (size_t)blockIdx.z * Cz;

  __shared__ bf16_t As[2][128 * 64];
  __shared__ bf16_t Bs[2][128 * 64];

  const int tid = threadIdx.x, w = tid >> 6, l = tid & 63;
  const int bm = blockIdx.y, bn = blockIdx.x;
  const int wm = (w >> 1) * 64, wn = (w & 1) * 64;
  const int lr = l & 15, lg = l >> 4;

  f32x4 acc[4][4] = {};

  auto stage = [&](int buf, int kt) {
#pragma unroll
    for (int j = 0; j < 4; j++) {
      int lin = (j * 4 + w) * 64 + l;       // 16B-chunk index 0..1023
      int row = lin >> 3, cc = lin & 7;
      const bf16_t* g = A + (size_t)(bm * 128 + row) * K + kt * 64 + cc * 8;
      __builtin_amdgcn_global_load_lds(
          (const __attribute__((address_space(1))) void*)g,
          (__attribute__((address_space(3))) void*)(&As[buf][(j * 4 + w) * 512]), 16, 0, 0);
    }
#pragma unroll
    for (int j = 0; j < 4; j++) {
      int lin = (j * 4 + w) * 64 + l;
      int row = lin >> 3, cc = lin & 7;
      const bf16_t* g = Bt + (size_t)(bn * 128 + row) * K + kt * 64 + cc * 8;
      __builtin_amdgcn_global_load_lds(
          (const __attribute__((address_space(1))) void*)g,
          (__attribute__((address_space(3))) void*)(&Bs[buf][(j * 4 + w) * 512]), 16, 0, 0);
    }
  };

  stage(0, 0);
  const int KT = K >> 6;
  for (int kt = 0; kt < KT; kt++) {
    __syncthreads();                         // drains vmcnt -> buf[kt&1] ready
    if (kt + 1 < KT) stage((kt + 1) & 1, kt + 1);
    const bf16_t* as = As[kt & 1];
    const bf16_t* bs = Bs[kt & 1];
#pragma unroll
    for (int kc = 0; kc < 2; kc++) {
      bf16x8 a[4], b[4];
#pragma unroll
      for (int i = 0; i < 4; i++)
        a[i] = *(const bf16x8*)(as + (wm + i * 16 + lr) * 64 + kc * 32 + lg * 8);
#pragma unroll
      for (int i = 0; i < 4; i++)
        b[i] = *(const bf16x8*)(bs + (wn + i * 16 + lr) * 64 + kc * 32 + lg * 8);
#pragma unroll
      for (int i = 0; i < 4; i++)
#pragma unroll
        for (int j = 0; j < 4; j++)
          acc[i][j] = __builtin_amdgcn_mfma_f32_16x16x32_bf16(a[i], b[j], acc[i][j], 0, 0, 0);
    }
  }

  // epilogue: C row = (lane>>4)*4+reg, col = lane&15 (verified m89/m91 layout)
  const int row0 = bm * 128 + wm, col0 = bn * 128 + wn;
#pragma unroll
  for (int j = 0; j < 4; j++) {
    int col = col0 + j * 16 + lr;
    float bv = bias[col];
#pragma unroll
    for (int i = 0; i < 4; i++) {
      int row = row0 + i * 16 + lg * 4;
#pragma unroll
      for (int r = 0; r < 4; r++) {
        float vv = acc[i][j][r] + bv;
        C[(size_t)(row + r) * N + col] = (OutT)vv;
      }
    }
  }
}

// ------------- flash attention per head-block -------------
// grid (32 qtiles, 16 bh), 256 thr (4 waves); QBLK=64 (16 q-rows/wave), KVBLK=64.
// Double-buffered K/V LDS, ONE barrier per KV-tile, async-STAGE split:
// global loads for tile t+1 issued right after the barrier, consumed (LDS
// write) after compute(t) -> HBM/L2 latency hidden under QK+softmax+PV.
// NOTE: reference divides by sqrt(DH)=8 AFTER softmax -> fold into epilogue.
__global__ __launch_bounds__(256) void attn_flash(const bf16_t* __restrict__ qp,
                                                  const bf16_t* __restrict__ kp,
                                                  const bf16_t* __restrict__ vp,
                                                  bf16_t* __restrict__ ctx) {
  const int qt = blockIdx.x, bh = blockIdx.y;
  const int tid = threadIdx.x, w = tid >> 6, l = tid & 63;
  const int lr = l & 15, lg = l >> 4;
  const size_t hb = (size_t)bh * (SS * DH);        // contiguous [2048,64] head block
  const bf16_t* Q = qp + hb;
  const bf16_t* Kh = kp + hb;
  const bf16_t* Vh = vp + hb;

  __shared__ bf16_t Ks[2][64][72];    // [kv][d], pad 72
  __shared__ bf16_t Vt[2][64][72];    // [d][kv] transposed
  __shared__ bf16_t Ps[4][16][72];    // per-wave P transpose buffer (same-wave RAW only)

  const int qr0 = qt * 64 + w * 16;

  // Q fragments held in registers for the whole kernel
  bf16x8 aq[2];
#pragma unroll
  for (int kc = 0; kc < 2; kc++)
    aq[kc] = *(const bf16x8*)(Q + (size_t)(qr0 + lr) * DH + kc * 32 + lg * 8);

  f32x4 o[4] = {};
  float m_r[4], l_r[4];
#pragma unroll
  for (int r = 0; r < 4; r++) { m_r[r] = -1e30f; l_r[r] = 0.f; }

  // fixed per-thread staging coordinates (chunks of 8 bf16)
  const int c0 = tid, c1 = 256 + tid;
  const int kr0 = c0 >> 3, kq0 = c0 & 7;
  const int kr1 = c1 >> 3, kq1 = c1 & 7;
  const int vk0 = c0 & 63, vd0 = (c0 >> 6) & 7;
  const int vk1 = c1 & 63, vd1 = (c1 >> 6) & 7;

  bf16x8 kreg0, kreg1, vreg0, vreg1;
  auto load_g = [&](int it) {
    const size_t kv0 = (size_t)it * 64;
    kreg0 = *(const bf16x8*)(Kh + (kv0 + kr0) * DH + kq0 * 8);
    kreg1 = *(const bf16x8*)(Kh + (kv0 + kr1) * DH + kq1 * 8);
    vreg0 = *(const bf16x8*)(Vh + (kv0 + vk0) * DH + vd0 * 8);
    vreg1 = *(const bf16x8*)(Vh + (kv0 + vk1) * DH + vd1 * 8);
  };
  auto write_lds = [&](int buf) {
    *(bf16x8*)(&Ks[buf][kr0][kq0 * 8]) = kreg0;
    *(bf16x8*)(&Ks[buf][kr1][kq1 * 8]) = kreg1;
#pragma unroll
    for (int j = 0; j < 8; j++) Vt[buf][vd0 * 8 + j][vk0] = vreg0[j];
#pragma unroll
    for (int j = 0; j < 8; j++) Vt[buf][vd1 * 8 + j][vk1] = vreg1[j];
  };

  load_g(0);
  write_lds(0);

  for (int it = 0; it < 32; it++) {
    const int buf = it & 1;
    __syncthreads();                 // publishes write_lds(it) from all waves;
                                     // vmcnt already drained by write_lds's reg use
    if (it + 1 < 32) load_g(it + 1); // issue next tile's loads; in flight during compute

    // --- S = Q @ K^T ---
    f32x4 s[4] = {};
    __builtin_amdgcn_s_setprio(1);
#pragma unroll
    for (int kc = 0; kc < 2; kc++) {
#pragma unroll
      for (int n = 0; n < 4; n++) {
        bf16x8 bk = *(const bf16x8*)(&Ks[buf][n * 16 + lr][kc * 32 + lg * 8]);
        s[n] = __builtin_amdgcn_mfma_f32_16x16x32_bf16(aq[kc], bk, s[n], 0, 0, 0);
      }
    }
    __builtin_amdgcn_s_setprio(0);

    // --- online softmax: row r lives in reg r across the 16 lanes of a group ---
    float p[4][4];
#pragma unroll
    for (int r = 0; r < 4; r++) {
      float tmax = fmaxf(fmaxf(s[0][r], s[1][r]), fmaxf(s[2][r], s[3][r]));
#pragma unroll
      for (int msk = 1; msk < 16; msk <<= 1) tmax = fmaxf(tmax, __shfl_xor(tmax, msk));
      float mnew = fmaxf(m_r[r], tmax);
      float scale = __expf(m_r[r] - mnew);
      float rs = 0.f;
#pragma unroll
      for (int n = 0; n < 4; n++) { p[n][r] = __expf(s[n][r] - mnew); rs += p[n][r]; }
#pragma unroll
      for (int msk = 1; msk < 16; msk <<= 1) rs += __shfl_xor(rs, msk);
      l_r[r] = l_r[r] * scale + rs;
      m_r[r] = mnew;
#pragma unroll
      for (int n = 0; n < 4; n++) o[n][r] *= scale;
    }

    // --- transpose P via per-wave LDS (same-wave RAW; no block barrier needed) ---
#pragma unroll
    for (int n = 0; n < 4; n++)
#pragma unroll
      for (int r = 0; r < 4; r++)
        Ps[w][lg * 4 + r][n * 16 + lr] = (bf16_t)p[n][r];

    // --- O += P @ V ---
    __builtin_amdgcn_s_setprio(1);
#pragma unroll
    for (int kc = 0; kc < 2; kc++) {
      bf16x8 pa = *(const bf16x8*)(&Ps[w][lr][kc * 32 + lg * 8]);
#pragma unroll
      for (int n = 0; n < 4; n++) {
        bf16x8 bv = *(const bf16x8*)(&Vt[buf][n * 16 + lr][kc * 32 + lg * 8]);
        o[n] = __builtin_amdgcn_mfma_f32_16x16x32_bf16(pa, bv, o[n], 0, 0, 0);
      }
    }
    __builtin_amdgcn_s_setprio(0);

    // consume the in-flight loads into the other buffer (vmcnt waits here,
    // mostly satisfied: loads were issued one full compute phase ago)
    if (it + 1 < 32) write_lds(buf ^ 1);
  }

  // epilogue: ctx[b*S + t][h*64 + d] = O / (l * 8)
  const int b = bh >> 3, h = bh & 7;
#pragma unroll
  for (int r = 0; r < 4; r++) {
    float inv = 1.0f / (l_r[r] * 8.0f);
    int t = qr0 + lg * 4 + r;
    size_t rowbase = ((size_t)b * SS + t) * 512 + h * 64;
#pragma unroll
    for (int n = 0; n < 4; n++)
      ctx[rowbase + n * 16 + lr] = (bf16_t)(o[n][r] * inv);
  }
}

// ---------------- launcher ----------------
extern "C" void kernel_launch(void* const* d_in, const int* in_sizes, int n_in,
                              void* d_out, int out_size, void* d_ws, size_t ws_size,
                              hipStream_t stream) {
  const float* q  = (const float*)d_in[0];
  const float* k  = (const float*)d_in[1];
  const float* v  = (const float*)d_in[2];
  const float* Wq = (const float*)d_in[3];
  const float* bq = (const float*)d_in[4];
  const float* Wk = (const float*)d_in[5];
  const float* bk = (const float*)d_in[6];
  const float* Wv = (const float*)d_in[7];
  const float* bv = (const float*)d_in[8];
  const float* Wo = (const float*)d_in[9];
  const float* bo = (const float*)d_in[10];

  const size_t NQKV = (size_t)4096 * 512;   // 2,097,152 elems per tensor
  const size_t NW = (size_t)512 * 512;

  bf16_t* ws  = (bf16_t*)d_ws;
  bf16_t* qkvb = ws;                 // 3*NQKV  (qb,kb,vb)
  bf16_t* wt   = qkvb + 3 * NQKV;    // 4*NW    (Wqt,Wkt,Wvt,Wot)
  bf16_t* proj = wt + 4 * NW;        // 3*NQKV  (qp,kp,vp)
  bf16_t* ctx  = proj + 3 * NQKV;    // NQKV
  // total 30 MB

  // 1. cast q,k,v -> bf16
  cast_qkv<<<dim3(1024, 1, 3), 256, 0, stream>>>(q, k, v, qkvb, (int)NQKV);
  // 2. transpose+cast weights
  transpose_w<<<dim3(16, 16, 4), dim3(32, 8), 0, stream>>>(Wq, Wk, Wv, Wo, wt);
  // 3. fused QKV projections (z-batched)
  gemm_bt<bf16_t><<<dim3(4, 32, 3), 256, 0, stream>>>(
      qkvb, wt, bq, bk, bv, proj, 4096, 512, 512, (long)NQKV, (long)NW, (long)NQKV);
  // 4. flash attention per head
  attn_flash<<<dim3(32, 16), 256, 0, stream>>>(proj, proj + NQKV, proj + 2 * NQKV, ctx);
  // 5. output projection (f32 out)
  gemm_bt<float><<<dim3(4, 32, 1), 256, 0, stream>>>(
      ctx, wt + 3 * NW, bo, bo, bo, (float*)d_out, 4096, 512, 512, 0, 0, 0);
}

// Round 3
// 91.403 us; speedup vs baseline: 1.3457x; 1.2096x over previous
//
#include <hip/hip_runtime.h>
#include <hip/hip_bf16.h>

typedef __bf16 bf16_t;
typedef __bf16 bf16x8 __attribute__((ext_vector_type(8)));
typedef __bf16 bf16x4 __attribute__((ext_vector_type(4)));
typedef short short4v __attribute__((ext_vector_type(4)));
typedef float f32x4 __attribute__((ext_vector_type(4)));

static_assert(sizeof(bf16x8) == 16, "bf16x8 must be 16B");

#if __has_builtin(__builtin_amdgcn_mfma_f32_16x16x16bf16_1k)
#define HAS_MFMA16 1
#else
#define HAS_MFMA16 0
#endif

// Problem constants
#define BB 2
#define SS 2048
#define DD 512
#define HH 8
#define DH 64
// HID == 512; head block = contiguous [2048,64] at (b*8+h)*131072

// ---------------- cast q,k,v f32 -> bf16 (vectorized) ----------------
__global__ void cast_qkv(const float* __restrict__ q, const float* __restrict__ k,
                         const float* __restrict__ v, bf16_t* __restrict__ dst, int n) {
  const float* src = (blockIdx.z == 0) ? q : (blockIdx.z == 1) ? k : v;
  bf16_t* out = dst + (size_t)blockIdx.z * n;
  int i = (blockIdx.x * 256 + threadIdx.x) * 8;
  if (i >= n) return;
  const float4* s4 = (const float4*)(src + i);
  float4 a = s4[0], b = s4[1];
  bf16x8 o;
  o[0] = (bf16_t)a.x; o[1] = (bf16_t)a.y; o[2] = (bf16_t)a.z; o[3] = (bf16_t)a.w;
  o[4] = (bf16_t)b.x; o[5] = (bf16_t)b.y; o[6] = (bf16_t)b.z; o[7] = (bf16_t)b.w;
  *(bf16x8*)(out + i) = o;
}

// ------------- transpose + cast weights: Wt[n][k] = (bf16)W[k][n] -------------
__global__ void transpose_w(const float* __restrict__ w0, const float* __restrict__ w1,
                            const float* __restrict__ w2, const float* __restrict__ w3,
                            bf16_t* __restrict__ wt) {
  __shared__ float tile[32][33];
  const float* W = (blockIdx.z == 0) ? w0 : (blockIdx.z == 1) ? w1 : (blockIdx.z == 2) ? w2 : w3;
  bf16_t* out = wt + (size_t)blockIdx.z * 512 * 512;
  int tx = threadIdx.x, ty = threadIdx.y;          // block (32,8)
  int nb = blockIdx.x * 32, kb = blockIdx.y * 32;
#pragma unroll
  for (int i = 0; i < 4; i++)
    tile[ty + i * 8][tx] = W[(size_t)(kb + ty + i * 8) * 512 + nb + tx];
  __syncthreads();
#pragma unroll
  for (int i = 0; i < 4; i++)
    out[(size_t)(nb + ty + i * 8) * 512 + kb + tx] = (bf16_t)tile[tx][ty + i * 8];
}

// ------------- GEMM: C[M,N] = A[M,K] @ Bt[N,K]^T + bias[N] -------------
// 128x128 tile, BK=64, 256 thr (4 waves 2x2), global_load_lds(16B), dbuf LDS.
template <typename OutT>
__global__ __launch_bounds__(256) void gemm_bt(
    const bf16_t* __restrict__ Abase, const bf16_t* __restrict__ Btbase,
    const float* __restrict__ bias0, const float* __restrict__ bias1,
    const float* __restrict__ bias2, OutT* __restrict__ Cbase,
    int M, int N, int K, long Az, long Bz, long Cz) {
  const bf16_t* A  = Abase + (size_t)blockIdx.z * Az;
  const bf16_t* Bt = Btbase + (size_t)blockIdx.z * Bz;
  const float* bias = (blockIdx.z == 0) ? bias0 : (blockIdx.z == 1) ? bias1 : bias2;
  OutT* C = Cbase + (size_t)blockIdx.z * Cz;

  __shared__ bf16_t As[2][128 * 64];
  __shared__ bf16_t Bs[2][128 * 64];

  const int tid = threadIdx.x, w = tid >> 6, l = tid & 63;
  const int bm = blockIdx.y, bn = blockIdx.x;
  const int wm = (w >> 1) * 64, wn = (w & 1) * 64;
  const int lr = l & 15, lg = l >> 4;

  f32x4 acc[4][4] = {};

  auto stage = [&](int buf, int kt) {
#pragma unroll
    for (int j = 0; j < 4; j++) {
      int lin = (j * 4 + w) * 64 + l;       // 16B-chunk index 0..1023
      int row = lin >> 3, cc = lin & 7;
      const bf16_t* g = A + (size_t)(bm * 128 + row) * K + kt * 64 + cc * 8;
      __builtin_amdgcn_global_load_lds(
          (const __attribute__((address_space(1))) void*)g,
          (__attribute__((address_space(3))) void*)(&As[buf][(j * 4 + w) * 512]), 16, 0, 0);
    }
#pragma unroll
    for (int j = 0; j < 4; j++) {
      int lin = (j * 4 + w) * 64 + l;
      int row = lin >> 3, cc = lin & 7;
      const bf16_t* g = Bt + (size_t)(bn * 128 + row) * K + kt * 64 + cc * 8;
      __builtin_amdgcn_global_load_lds(
          (const __attribute__((address_space(1))) void*)g,
          (__attribute__((address_space(3))) void*)(&Bs[buf][(j * 4 + w) * 512]), 16, 0, 0);
    }
  };

  stage(0, 0);
  const int KT = K >> 6;
  for (int kt = 0; kt < KT; kt++) {
    __syncthreads();                         // drains vmcnt -> buf[kt&1] ready
    if (kt + 1 < KT) stage((kt + 1) & 1, kt + 1);
    const bf16_t* as = As[kt & 1];
    const bf16_t* bs = Bs[kt & 1];
#pragma unroll
    for (int kc = 0; kc < 2; kc++) {
      bf16x8 a[4], b[4];
#pragma unroll
      for (int i = 0; i < 4; i++)
        a[i] = *(const bf16x8*)(as + (wm + i * 16 + lr) * 64 + kc * 32 + lg * 8);
#pragma unroll
      for (int i = 0; i < 4; i++)
        b[i] = *(const bf16x8*)(bs + (wn + i * 16 + lr) * 64 + kc * 32 + lg * 8);
#pragma unroll
      for (int i = 0; i < 4; i++)
#pragma unroll
        for (int j = 0; j < 4; j++)
          acc[i][j] = __builtin_amdgcn_mfma_f32_16x16x32_bf16(a[i], b[j], acc[i][j], 0, 0, 0);
    }
  }

  // epilogue: C row = (lane>>4)*4+reg, col = lane&15 (verified m89/m91 layout)
  const int row0 = bm * 128 + wm, col0 = bn * 128 + wn;
#pragma unroll
  for (int j = 0; j < 4; j++) {
    int col = col0 + j * 16 + lr;
    float bv = bias[col];
#pragma unroll
    for (int i = 0; i < 4; i++) {
      int row = row0 + i * 16 + lg * 4;
#pragma unroll
      for (int r = 0; r < 4; r++) {
        float vv = acc[i][j][r] + bv;
        C[(size_t)(row + r) * N + col] = (OutT)vv;
      }
    }
  }
}

// ------------- flash attention per head-block -------------
// grid (32 qtiles, 16 bh), 256 thr (4 waves); QBLK=64 (16 q-rows/wave), KVBLK=64.
// Swapped QK^T (S^T = mfma(K,Q)) -> each lane owns one q-row's 16 S-values:
// softmax is in-lane + 2 shfl_xor; O accumulated transposed (O^T[d][q]);
// P^T feeds PV directly from registers via 16x16x16 MFMA (k-slice == owner
// layout) -> no P LDS round trip, no butterfly reductions.
// NOTE: reference divides by sqrt(DH)=8 AFTER softmax -> fold into epilogue.
__global__ __launch_bounds__(256) void attn_flash(const bf16_t* __restrict__ qp,
                                                  const bf16_t* __restrict__ kp,
                                                  const bf16_t* __restrict__ vp,
                                                  bf16_t* __restrict__ ctx) {
  const int qt = blockIdx.x, bh = blockIdx.y;
  const int tid = threadIdx.x, w = tid >> 6, l = tid & 63;
  const int lr = l & 15, lg = l >> 4;
  const size_t hb = (size_t)bh * (SS * DH);        // contiguous [2048,64] head block
  const bf16_t* Q = qp + hb;
  const bf16_t* Kh = kp + hb;
  const bf16_t* Vh = vp + hb;

  __shared__ bf16_t Ks[2][64][72];    // [kv][d], pad 72
  __shared__ bf16_t Vt[2][64][72];    // [d][kv] transposed
#if !HAS_MFMA16
  __shared__ bf16_t Pq[4][16][72];    // fallback: per-wave P[q][kv] buffer
#endif

  const int qr0 = qt * 64 + w * 16;

  // Q fragment (B-operand: col=lr, k=lg*8+j) held for the whole kernel
  bf16x8 aq[2];
#pragma unroll
  for (int kc = 0; kc < 2; kc++)
    aq[kc] = *(const bf16x8*)(Q + (size_t)(qr0 + lr) * DH + kc * 32 + lg * 8);

  f32x4 o[4] = {};                    // O^T[d = n*16+lg*4+r][q = lr]
  float m_run = -1e30f, l_run = 0.f;  // per-lane scalars (row q = lr)

  // fixed per-thread staging coordinates (chunks of 8 bf16)
  const int c0 = tid, c1 = 256 + tid;
  const int kr0 = c0 >> 3, kq0 = c0 & 7;
  const int kr1 = c1 >> 3, kq1 = c1 & 7;
  const int vk0 = c0 & 63, vd0 = (c0 >> 6) & 7;
  const int vk1 = c1 & 63, vd1 = (c1 >> 6) & 7;

  bf16x8 kreg0, kreg1, vreg0, vreg1;
  auto load_g = [&](int it) {
    const size_t kv0 = (size_t)it * 64;
    kreg0 = *(const bf16x8*)(Kh + (kv0 + kr0) * DH + kq0 * 8);
    kreg1 = *(const bf16x8*)(Kh + (kv0 + kr1) * DH + kq1 * 8);
    vreg0 = *(const bf16x8*)(Vh + (kv0 + vk0) * DH + vd0 * 8);
    vreg1 = *(const bf16x8*)(Vh + (kv0 + vk1) * DH + vd1 * 8);
  };
  auto write_lds = [&](int buf) {
    *(bf16x8*)(&Ks[buf][kr0][kq0 * 8]) = kreg0;
    *(bf16x8*)(&Ks[buf][kr1][kq1 * 8]) = kreg1;
#pragma unroll
    for (int j = 0; j < 8; j++) Vt[buf][vd0 * 8 + j][vk0] = vreg0[j];
#pragma unroll
    for (int j = 0; j < 8; j++) Vt[buf][vd1 * 8 + j][vk1] = vreg1[j];
  };

  load_g(0);
  write_lds(0);

  for (int it = 0; it < 32; it++) {
    const int buf = it & 1;
    __syncthreads();                 // publishes write_lds(it) from all waves
    if (it + 1 < 32) load_g(it + 1); // next tile's loads fly during compute

    // --- S^T = K @ Q^T : s[n][r] = S[kv = n*16+lg*4+r][q = lr] ---
    f32x4 s[4] = {};
    __builtin_amdgcn_s_setprio(1);
#pragma unroll
    for (int kc = 0; kc < 2; kc++) {
#pragma unroll
      for (int n = 0; n < 4; n++) {
        bf16x8 bk = *(const bf16x8*)(&Ks[buf][n * 16 + lr][kc * 32 + lg * 8]);
        s[n] = __builtin_amdgcn_mfma_f32_16x16x32_bf16(bk, aq[kc], s[n], 0, 0, 0);
      }
    }
    __builtin_amdgcn_s_setprio(0);

    // --- in-register online softmax (row q=lr: 16 in-lane vals + lanes lr+16k) ---
    float pmax = -1e30f;
#pragma unroll
    for (int n = 0; n < 4; n++)
#pragma unroll
      for (int r = 0; r < 4; r++) pmax = fmaxf(pmax, s[n][r]);
    pmax = fmaxf(pmax, __shfl_xor(pmax, 16));
    pmax = fmaxf(pmax, __shfl_xor(pmax, 32));
    float mnew = fmaxf(m_run, pmax);
    float scale = __expf(m_run - mnew);
    m_run = mnew;
    float rs = 0.f;
#pragma unroll
    for (int n = 0; n < 4; n++)
#pragma unroll
      for (int r = 0; r < 4; r++) {
        float e = __expf(s[n][r] - mnew);
        s[n][r] = e;
        rs += e;
      }
    rs += __shfl_xor(rs, 16);
    rs += __shfl_xor(rs, 32);
    l_run = l_run * scale + rs;

#if HAS_MFMA16
    // rescale O^T (uniform per lane) and run PV from registers:
    // o[n] (d-block n) += sum over kv-chunks c2: V^T[d][kv] * P^T[kv][q]
#pragma unroll
    for (int n = 0; n < 4; n++)
#pragma unroll
      for (int r = 0; r < 4; r++) o[n][r] *= scale;
    short4v pb[4];
#pragma unroll
    for (int n = 0; n < 4; n++) {
      bf16x4 t;
#pragma unroll
      for (int r = 0; r < 4; r++) t[r] = (bf16_t)s[n][r];
      pb[n] = __builtin_bit_cast(short4v, t);
    }
    __builtin_amdgcn_s_setprio(1);
#pragma unroll
    for (int n = 0; n < 4; n++) {
#pragma unroll
      for (int c2 = 0; c2 < 4; c2++) {
        bf16x4 bvh = *(const bf16x4*)(&Vt[buf][n * 16 + lr][c2 * 16 + lg * 4]);
        o[n] = __builtin_amdgcn_mfma_f32_16x16x16bf16_1k(
            __builtin_bit_cast(short4v, bvh), pb[c2], o[n], 0, 0, 0);
      }
    }
    __builtin_amdgcn_s_setprio(0);
#else
    // fallback: broadcast scale to C-layout rows, P via per-wave LDS, x32 PV
#pragma unroll
    for (int r = 0; r < 4; r++) {
      float sc = __shfl(scale, lg * 4 + r);
#pragma unroll
      for (int n = 0; n < 4; n++) o[n][r] *= sc;
    }
#pragma unroll
    for (int n = 0; n < 4; n++)
#pragma unroll
      for (int r = 0; r < 4; r++)
        Pq[w][lr][n * 16 + lg * 4 + r] = (bf16_t)s[n][r];
    __builtin_amdgcn_s_setprio(1);
#pragma unroll
    for (int kc = 0; kc < 2; kc++) {
      bf16x8 pa = *(const bf16x8*)(&Pq[w][lr][kc * 32 + lg * 8]);
#pragma unroll
      for (int n = 0; n < 4; n++) {
        bf16x8 bv = *(const bf16x8*)(&Vt[buf][n * 16 + lr][kc * 32 + lg * 8]);
        o[n] = __builtin_amdgcn_mfma_f32_16x16x32_bf16(pa, bv, o[n], 0, 0, 0);
      }
    }
    __builtin_amdgcn_s_setprio(0);
#endif

    // consume in-flight loads into the other buffer
    if (it + 1 < 32) write_lds(buf ^ 1);
  }

  // epilogue: ctx[b*S + t][h*64 + d] = O / (l * 8)
  const int b = bh >> 3, h = bh & 7;
#if HAS_MFMA16
  {
    float inv = 1.0f / (l_run * 8.0f);
    int t = qr0 + lr;
    size_t rowbase = ((size_t)b * SS + t) * 512 + h * 64;
#pragma unroll
    for (int n = 0; n < 4; n++) {
      bf16x4 ov;
#pragma unroll
      for (int r = 0; r < 4; r++) ov[r] = (bf16_t)(o[n][r] * inv);
      *(bf16x4*)(&ctx[rowbase + n * 16 + lg * 4]) = ov;
    }
  }
#else
#pragma unroll
  for (int r = 0; r < 4; r++) {
    float li = __shfl(l_run, lg * 4 + r);
    float inv = 1.0f / (li * 8.0f);
    int t = qr0 + lg * 4 + r;
    size_t rowbase = ((size_t)b * SS + t) * 512 + h * 64;
#pragma unroll
    for (int n = 0; n < 4; n++)
      ctx[rowbase + n * 16 + lr] = (bf16_t)(o[n][r] * inv);
  }
#endif
}

// ---------------- launcher ----------------
extern "C" void kernel_launch(void* const* d_in, const int* in_sizes, int n_in,
                              void* d_out, int out_size, void* d_ws, size_t ws_size,
                              hipStream_t stream) {
  const float* q  = (const float*)d_in[0];
  const float* k  = (const float*)d_in[1];
  const float* v  = (const float*)d_in[2];
  const float* Wq = (const float*)d_in[3];
  const float* bq = (const float*)d_in[4];
  const float* Wk = (const float*)d_in[5];
  const float* bk = (const float*)d_in[6];
  const float* Wv = (const float*)d_in[7];
  const float* bv = (const float*)d_in[8];
  const float* Wo = (const float*)d_in[9];
  const float* bo = (const float*)d_in[10];

  const size_t NQKV = (size_t)4096 * 512;   // 2,097,152 elems per tensor
  const size_t NW = (size_t)512 * 512;

  bf16_t* ws  = (bf16_t*)d_ws;
  bf16_t* qkvb = ws;                 // 3*NQKV  (qb,kb,vb)
  bf16_t* wt   = qkvb + 3 * NQKV;    // 4*NW    (Wqt,Wkt,Wvt,Wot)
  bf16_t* proj = wt + 4 * NW;        // 3*NQKV  (qp,kp,vp)
  bf16_t* ctx  = proj + 3 * NQKV;    // NQKV
  // total 30 MB

  // 1. cast q,k,v -> bf16
  cast_qkv<<<dim3(1024, 1, 3), 256, 0, stream>>>(q, k, v, qkvb, (int)NQKV);
  // 2. transpose+cast weights
  transpose_w<<<dim3(16, 16, 4), dim3(32, 8), 0, stream>>>(Wq, Wk, Wv, Wo, wt);
  // 3. fused QKV projections (z-batched)
  gemm_bt<bf16_t><<<dim3(4, 32, 3), 256, 0, stream>>>(
      qkvb, wt, bq, bk, bv, proj, 4096, 512, 512, (long)NQKV, (long)NW, (long)NQKV);
  // 4. flash attention per head
  attn_flash<<<dim3(32, 16), 256, 0, stream>>>(proj, proj + NQKV, proj + 2 * NQKV, ctx);
  // 5. output projection (f32 out)
  gemm_bt<float><<<dim3(4, 32, 1), 256, 0, stream>>>(
      ctx, wt + 3 * NW, bo, bo, bo, (float*)d_out, 4096, 512, 512, 0, 0, 0);
}